// Round 7
// baseline (169.806 us; speedup 1.0000x reference)
//
#include <hip/hip_runtime.h>
#include <math.h>

#define BB 512       // batch rows (M)
#define DD 512       // depth (K)
#define CC 100000    // classes (N)
#define MARGIN2 0.5f
#define PI_F 3.14159265358979323846f

#define BM 256
#define BN 128
#define BK 64
#define KSTEPS (DD / BK)     // 8
#define NPAN 782             // ceil(100000/128), last panel 32 cols
#define GRID (2 * NPAN)      // 1564 blocks

typedef __bf16 bf16x8 __attribute__((ext_vector_type(8)));
typedef float f32x4 __attribute__((ext_vector_type(4)));

static __device__ __forceinline__ unsigned short f2bf(float f) {
    union { float f; unsigned u; } v; v.f = f;
    unsigned r = v.u + 0x7FFFu + ((v.u >> 16) & 1u);   // round-to-nearest-even
    return (unsigned short)(r >> 16);
}

// swizzled LDS byte offset for row-major [row][64 x bf16] tiles (row stride 128B)
static __device__ __forceinline__ int swz(int row, int kbyte) {
    return row * 128 + (kbyte ^ ((row & 7) << 4));
}

// async global->LDS, 16B per lane; LDS dest = wave-uniform base + lane*16 (HW rule)
static __device__ __forceinline__ void gll16(const unsigned char* g, unsigned char* l) {
    __builtin_amdgcn_global_load_lds(
        (const __attribute__((address_space(1))) void*)g,
        (__attribute__((address_space(3))) void*)l, 16, 0, 0);
}

// ---------------- K1: row-normalize x -> bf16, PRE-SWIZZLED A images ----------------
// Image layout (BM=256): img[(mb*8 + t)*32768 + swz(lrow, c8*16) + sub*8], so the
// GEMM's linear global_load_lds reproduces the swizzled Ash layout exactly (m173).
__global__ __launch_bounds__(256) void k_norm_x(const float* __restrict__ x,
                                                unsigned char* __restrict__ img) {
    const int lane = threadIdx.x & 63;
    const int row  = blockIdx.x * 4 + (threadIdx.x >> 6);
    const float* xr = x + (size_t)row * DD;
    float4 v0 = *(const float4*)(xr + lane * 4);
    float4 v1 = *(const float4*)(xr + lane * 4 + 256);
    float s = v0.x*v0.x + v0.y*v0.y + v0.z*v0.z + v0.w*v0.w
            + v1.x*v1.x + v1.y*v1.y + v1.z*v1.z + v1.w*v1.w;
    #pragma unroll
    for (int m = 32; m; m >>= 1) s += __shfl_xor(s, m, 64);
    float rs = rsqrtf(fmaxf(s, 1e-12f));
    ushort4 o0, o1;
    o0.x = f2bf(v0.x * rs); o0.y = f2bf(v0.y * rs);
    o0.z = f2bf(v0.z * rs); o0.w = f2bf(v0.w * rs);
    o1.x = f2bf(v1.x * rs); o1.y = f2bf(v1.y * rs);
    o1.z = f2bf(v1.z * rs); o1.w = f2bf(v1.w * rs);

    const int mb   = row >> 8;            // which 256-row M block
    const int lrow = row & 255;
    const int k0   = lane * 4;            // v0 covers k0..k0+3; v1 covers k0+256..
    const int t0   = k0 >> 6;             // 0..3 (v1 -> t0+4)
    const int c8   = (k0 >> 3) & 7;       // 16B chunk within 128B row
    const int sub  = (k0 >> 2) & 1;       // 8B half of the chunk
    const int base = (mb * 8 + t0) * 32768 + lrow * 128
                   + ((c8 * 16) ^ ((lrow & 7) << 4)) + sub * 8;
    *(ushort4*)(img + base)          = o0;
    *(ushort4*)(img + base + 131072) = o1;   // t0+4 image (4 * 32768)
}

// ---------------- K2: bf16 MFMA GEMM, 256x128 tile, single-barrier pipelined loop ----
// LDS: bufA = 2 x 32KB dbuf (gll from pre-swizzled image)
//      bufB = 2 x 16KB dbuf ([n][64k] bf16 swizzled, cvt_pk from fp32 W regs)
//      rn   = 512B dedicated
// After K loop: bufB head -> part[16][128]; bufA head -> store staging (32x132 f32).
#define LDSZ (65536 + 32768 + 512)   // 98816 -> 1 block/CU (160KB budget)

__global__ __launch_bounds__(512, 2) void k_gemm(const unsigned char* __restrict__ img,
                                                 const float* __restrict__ W,
                                                 float* __restrict__ out) {
    __shared__ __align__(16) unsigned char LDS[LDSZ];
    unsigned char* bufA = LDS;                  // 2 x 32768
    unsigned char* bufB = LDS + 65536;          // 2 x 16384
    float* rn = (float*)(LDS + 98304);

    const int tid = threadIdx.x;
    const int bid = blockIdx.x;

    // bijective XCD swizzle (1564 = 8*195 + 4): mb-pairs of a W panel share one XCD's L2
    const int xcd = bid & 7;
    const int jj  = bid >> 3;
    const int v   = (xcd < 4) ? (xcd * 196 + jj) : (784 + (xcd - 4) * 195 + jj);
    const int mb  = v & 1;
    const int nb  = v >> 1;
    const int M0 = mb * BM;
    const int N0 = nb * BN;

    const int lane = tid & 63;
    const int wid  = tid >> 6;     // 0..7
    const int wm = wid >> 1;       // 0..3 -> 64 rows each
    const int wn = wid & 1;        // 0..1 -> 64 cols each
    const int lr = lane & 15;
    const int lg = lane >> 4;

    // ---- B staging tasks: 4 per thread; s = kq*128 + n (bijective, also part[] slot) ----
    int b_go[4], b_ld[4];
    #pragma unroll
    for (int i = 0; i < 4; ++i) {
        int s  = tid + i * 512;
        int n  = s & 127;
        int kq = s >> 7;                       // 0..15, quad of k
        int col = N0 + n;
        col = col < CC ? col : CC - 1;         // tail-panel clamp (dead cols)
        b_go[i] = kq * 4 * CC + col;
        b_ld[i] = n * 128 + ((kq * 8) ^ ((n & 7) << 4));
    }

    const unsigned char* imgA = img + mb * (8 * 32768);
    const int lds_u = wid * 1024;              // wave-uniform part of linear offset

    float breg[4][4];
    float bsq[4] = {0.f, 0.f, 0.f, 0.f};

    // ---- prologue: stage tile 0 completely ----
    #pragma unroll
    for (int i = 0; i < 4; ++i) {
        const float* p = W + b_go[i];
        breg[i][0] = p[0]; breg[i][1] = p[CC];
        breg[i][2] = p[2 * CC]; breg[i][3] = p[3 * CC];
    }
    #pragma unroll
    for (int i = 0; i < 4; ++i)
        gll16(imgA + i * 8192 + lds_u + lane * 16, bufA + i * 8192 + lds_u);
    #pragma unroll
    for (int i = 0; i < 4; ++i) {
        bsq[i] += breg[i][0] * breg[i][0] + breg[i][1] * breg[i][1]
                + breg[i][2] * breg[i][2] + breg[i][3] * breg[i][3];
        unsigned w0, w1;
        asm("v_cvt_pk_bf16_f32 %0, %1, %2" : "=v"(w0) : "v"(breg[i][0]), "v"(breg[i][1]));
        asm("v_cvt_pk_bf16_f32 %0, %1, %2" : "=v"(w1) : "v"(breg[i][2]), "v"(breg[i][3]));
        uint2 w; w.x = w0; w.y = w1;
        *(uint2*)(bufB + b_ld[i]) = w;
    }
    asm volatile("s_waitcnt vmcnt(0)" ::: "memory");
    __builtin_amdgcn_sched_barrier(0);
    asm volatile("s_waitcnt lgkmcnt(0)" ::: "memory");
    __builtin_amdgcn_sched_barrier(0);
    __builtin_amdgcn_s_barrier();
    __builtin_amdgcn_sched_barrier(0);

    f32x4 acc[4][4];
    #pragma unroll
    for (int mf = 0; mf < 4; ++mf)
        #pragma unroll
        for (int nf = 0; nf < 4; ++nf)
            acc[mf][nf] = (f32x4)0.f;

    for (int t = 0; t < KSTEPS; ++t) {
        const int cur = t & 1;
        unsigned char* A_cur = bufA + cur * 32768;
        unsigned char* B_cur = bufB + cur * 16384;

        // phase 1: issue next tile's loads (stay in flight through compute)
        if (t + 1 < KSTEPS) {
            #pragma unroll
            for (int i = 0; i < 4; ++i) {
                const float* p = W + b_go[i] + (t + 1) * (BK * CC);
                breg[i][0] = p[0]; breg[i][1] = p[CC];
                breg[i][2] = p[2 * CC]; breg[i][3] = p[3 * CC];
            }
            unsigned char* A_nxt = bufA + (cur ^ 1) * 32768;
            const unsigned char* gsrc = imgA + (t + 1) * 32768;
            #pragma unroll
            for (int i = 0; i < 4; ++i)
                gll16(gsrc + i * 8192 + lds_u + lane * 16, A_nxt + i * 8192 + lds_u);
            __builtin_amdgcn_sched_barrier(0);   // pin load-issue before compute
        }

        // phase 2: compute tile t (ds_read + MFMA, compiler-scheduled lgkmcnt)
        #pragma unroll
        for (int ks = 0; ks < 2; ++ks) {
            bf16x8 af[4], bfr[4];
            #pragma unroll
            for (int mf = 0; mf < 4; ++mf)
                af[mf] = *(const bf16x8*)(A_cur + swz(wm * 64 + mf * 16 + lr, ks * 64 + lg * 16));
            #pragma unroll
            for (int nf = 0; nf < 4; ++nf)
                bfr[nf] = *(const bf16x8*)(B_cur + swz(wn * 64 + nf * 16 + lr, ks * 64 + lg * 16));
            #pragma unroll
            for (int mf = 0; mf < 4; ++mf)
                #pragma unroll
                for (int nf = 0; nf < 4; ++nf)
                    acc[mf][nf] = __builtin_amdgcn_mfma_f32_16x16x32_bf16(
                        bfr[nf], af[mf], acc[mf][nf], 0, 0, 0);
        }

        // phase 3: write B(t+1) (auto vmcnt wait on breg only; glls stay in flight)
        if (t + 1 < KSTEPS) {
            unsigned char* B_nxt = bufB + (cur ^ 1) * 16384;
            #pragma unroll
            for (int i = 0; i < 4; ++i) {
                bsq[i] += breg[i][0] * breg[i][0] + breg[i][1] * breg[i][1]
                        + breg[i][2] * breg[i][2] + breg[i][3] * breg[i][3];
                unsigned w0, w1;
                asm("v_cvt_pk_bf16_f32 %0, %1, %2" : "=v"(w0) : "v"(breg[i][0]), "v"(breg[i][1]));
                asm("v_cvt_pk_bf16_f32 %0, %1, %2" : "=v"(w1) : "v"(breg[i][2]), "v"(breg[i][3]));
                uint2 w; w.x = w0; w.y = w1;
                *(uint2*)(B_nxt + b_ld[i]) = w;
            }
            // phase 4: single drain + barrier per K-step, after maximal overlap
            asm volatile("s_waitcnt vmcnt(0)" ::: "memory");
            __builtin_amdgcn_sched_barrier(0);
            asm volatile("s_waitcnt lgkmcnt(0)" ::: "memory");
            __builtin_amdgcn_sched_barrier(0);
            __builtin_amdgcn_s_barrier();
            __builtin_amdgcn_sched_barrier(0);
        }
    }

    // ---- deterministic column-norm reduction (reuse bufB) ----
    __syncthreads();
    float* part = (float*)bufB;                // [16][128] floats = 8KB
    #pragma unroll
    for (int i = 0; i < 4; ++i)
        part[tid + i * 512] = bsq[i];          // slot = kq*128+n, unique owner
    __syncthreads();
    if (tid < BN) {
        float s = 0.f;
        #pragma unroll
        for (int k = 0; k < 16; ++k)
            s += part[k * BN + tid];           // fixed order -> deterministic
        rn[tid] = rsqrtf(fmaxf(s, 1e-12f));
    }
    __syncthreads();

    // ---- epilogue: LDS-staged -> 512B-aligned full-sector row stores ----
    float* stag = (float*)bufA;                // 32 rows x 132 floats
    #pragma unroll
    for (int rd = 0; rd < 8; ++rd) {
        if (wm == (rd >> 1)) {
            #pragma unroll
            for (int f = 0; f < 2; ++f) {
                const int mf = (rd & 1) * 2 + f;
                const int ml = f * 16 + lr;
                #pragma unroll
                for (int nf = 0; nf < 4; ++nf) {
                    const int nl = wn * 64 + nf * 16 + lg * 4;
                    const f32x4 rn4 = *(const f32x4*)(rn + nl);
                    f32x4 o;
                    #pragma unroll
                    for (int r = 0; r < 4; ++r)
                        o[r] = acc[mf][nf][r] * rn4[r];
                    *(f32x4*)(stag + ml * 132 + nl) = o;
                }
            }
        }
        __syncthreads();
        #pragma unroll
        for (int j = tid; j < 1024; j += 512) {
            const int m = j >> 5;
            const int n = (j & 31) * 4;
            if (N0 + n + 4 <= CC) {
                f32x4 o = *(const f32x4*)(stag + m * 132 + n);
                *(f32x4*)(out + (size_t)(M0 + rd * 32 + m) * CC + N0 + n) = o;
            }
        }
        __syncthreads();
    }
}

// ---------------- K3: margin fixup at label positions ----------------
__global__ __launch_bounds__(512) void k_fix(const int* __restrict__ lab,
                                             float* __restrict__ out) {
    const int b = threadIdx.x;
    const int c = lab[b];
    const size_t idx = (size_t)b * CC + c;
    float t = out[idx];
    t = fminf(fmaxf(t, -1.f), 1.f);
    float th = acosf(t) + MARGIN2;
    th = fminf(th, PI_F);              // min(t, t + (pi - stopgrad(t))) value-wise
    out[idx] = cosf(th);               // M3 == 0: no additive term
}

extern "C" void kernel_launch(void* const* d_in, const int* in_sizes, int n_in,
                              void* d_out, int out_size, void* d_ws, size_t ws_size,
                              hipStream_t stream) {
    const float* x   = (const float*)d_in[0];
    const float* W   = (const float*)d_in[1];
    const int*   lab = (const int*)d_in[2];
    float* out = (float*)d_out;

    unsigned char* img = (unsigned char*)d_ws;   // 512KB pre-swizzled xn images

    k_norm_x<<<dim3(BB / 4), dim3(256), 0, stream>>>(x, img);
    k_gemm<<<dim3(GRID), dim3(512), 0, stream>>>(img, W, out);
    k_fix<<<dim3(1), dim3(512), 0, stream>>>(lab, out);
}

// Round 8
// 117.215 us; speedup vs baseline: 1.4487x; 1.4487x over previous
//
#include <hip/hip_runtime.h>
#include <math.h>

#define BB 512       // batch rows (M)
#define DD 512       // depth (K)
#define CC 100000    // classes (N)
#define MARGIN2 0.5f
#define PI_F 3.14159265358979323846f

#define BM 256
#define BN 128
#define BK 64
#define KSTEPS (DD / BK)     // 8
#define NPAN 782             // ceil(100000/128), last panel 32 cols
#define GRID (2 * NPAN)      // 1564 blocks

typedef __bf16 bf16x8 __attribute__((ext_vector_type(8)));
typedef float f32x4 __attribute__((ext_vector_type(4)));

static __device__ __forceinline__ unsigned short f2bf(float f) {
    union { float f; unsigned u; } v; v.f = f;
    unsigned r = v.u + 0x7FFFu + ((v.u >> 16) & 1u);   // round-to-nearest-even
    return (unsigned short)(r >> 16);
}

// swizzled LDS byte offset for row-major [row][64 x bf16] tiles (row stride 128B)
static __device__ __forceinline__ int swz(int row, int kbyte) {
    return row * 128 + (kbyte ^ ((row & 7) << 4));
}

// async global->LDS, 16B per lane; LDS dest = wave-uniform base + lane*16 (HW rule)
static __device__ __forceinline__ void gll16(const unsigned char* g, unsigned char* l) {
    __builtin_amdgcn_global_load_lds(
        (const __attribute__((address_space(1))) void*)g,
        (__attribute__((address_space(3))) void*)l, 16, 0, 0);
}

// ---------------- K1: row-normalize x -> bf16, PRE-SWIZZLED A images ----------------
// Image layout (BM=256): img[(mb*8 + t)*32768 + swz(lrow, c8*16) + sub*8], so the
// GEMM's linear global_load_lds reproduces the swizzled Ash layout exactly (m173).
__global__ __launch_bounds__(256) void k_norm_x(const float* __restrict__ x,
                                                unsigned char* __restrict__ img) {
    const int lane = threadIdx.x & 63;
    const int row  = blockIdx.x * 4 + (threadIdx.x >> 6);
    const float* xr = x + (size_t)row * DD;
    float4 v0 = *(const float4*)(xr + lane * 4);
    float4 v1 = *(const float4*)(xr + lane * 4 + 256);
    float s = v0.x*v0.x + v0.y*v0.y + v0.z*v0.z + v0.w*v0.w
            + v1.x*v1.x + v1.y*v1.y + v1.z*v1.z + v1.w*v1.w;
    #pragma unroll
    for (int m = 32; m; m >>= 1) s += __shfl_xor(s, m, 64);
    float rs = rsqrtf(fmaxf(s, 1e-12f));
    ushort4 o0, o1;
    o0.x = f2bf(v0.x * rs); o0.y = f2bf(v0.y * rs);
    o0.z = f2bf(v0.z * rs); o0.w = f2bf(v0.w * rs);
    o1.x = f2bf(v1.x * rs); o1.y = f2bf(v1.y * rs);
    o1.z = f2bf(v1.z * rs); o1.w = f2bf(v1.w * rs);

    const int mb   = row >> 8;            // which 256-row M block
    const int lrow = row & 255;
    const int k0   = lane * 4;            // v0 covers k0..k0+3; v1 covers k0+256..
    const int t0   = k0 >> 6;             // 0..3 (v1 -> t0+4)
    const int c8   = (k0 >> 3) & 7;       // 16B chunk within 128B row
    const int sub  = (k0 >> 2) & 1;       // 8B half of the chunk
    const int base = (mb * 8 + t0) * 32768 + lrow * 128
                   + ((c8 * 16) ^ ((lrow & 7) << 4)) + sub * 8;
    *(ushort4*)(img + base)          = o0;
    *(ushort4*)(img + base + 131072) = o1;   // t0+4 image (4 * 32768)
}

// ---------------- K2: bf16 MFMA GEMM, 256x128 tile, depth-2 counted-vmcnt pipeline ----
// LDS: bufA = 2 x 32KB dbuf (gll from pre-swizzled image)
//      bufB = 2 x 16KB dbuf ([n][64k] bf16 swizzled, cvt_pk from fp32 W regs)
//      rn   = 512B dedicated
// Pipeline (per iter t): issue A(t+1) glls FIRST, then B(t+2) reg-loads (in-order
// vmcnt!), compute t, write B(t+1) from regs loaded 2 iters ago (compiler emits
// counted vmcnt ~20), then s_waitcnt vmcnt(16) -> drains A(t+1) glls, LEAVES
// B(t+2):16 in flight across the barrier. Never vmcnt(0) in steady state (T4).
#define LDSZ (65536 + 32768 + 512)   // 98816 -> 1 block/CU

__global__ __launch_bounds__(512, 2) void k_gemm(const unsigned char* __restrict__ img,
                                                 const float* __restrict__ W,
                                                 float* __restrict__ out) {
    __shared__ __align__(16) unsigned char LDS[LDSZ];
    unsigned char* bufA = LDS;                  // 2 x 32768
    unsigned char* bufB = LDS + 65536;          // 2 x 16384
    float* rn = (float*)(LDS + 98304);

    const int tid = threadIdx.x;
    const int bid = blockIdx.x;

    // bijective XCD swizzle (1564 = 8*195 + 4): mb-pairs of a W panel share one XCD's L2
    const int xcd = bid & 7;
    const int jj  = bid >> 3;
    const int v   = (xcd < 4) ? (xcd * 196 + jj) : (784 + (xcd - 4) * 195 + jj);
    const int mb  = v & 1;
    const int nb  = v >> 1;
    const int M0 = mb * BM;
    const int N0 = nb * BN;

    const int lane = tid & 63;
    const int wid  = tid >> 6;     // 0..7
    const int wm = wid >> 1;       // 0..3 -> 64 rows each
    const int wn = wid & 1;        // 0..1 -> 64 cols each
    const int lr = lane & 15;
    const int lg = lane >> 4;

    // ---- B staging tasks: 4 per thread; s = kq*128 + n (bijective, also part[] slot) ----
    int b_go[4], b_ld[4];
    #pragma unroll
    for (int i = 0; i < 4; ++i) {
        int s  = tid + i * 512;
        int n  = s & 127;
        int kq = s >> 7;                       // 0..15, quad of k
        int col = N0 + n;
        col = col < CC ? col : CC - 1;         // tail-panel clamp (dead cols)
        b_go[i] = kq * 4 * CC + col;
        b_ld[i] = n * 128 + ((kq * 8) ^ ((n & 7) << 4));
    }

    const unsigned char* imgA = img + mb * (8 * 32768);
    const int lds_u = wid * 1024;              // wave-uniform part of linear offset

    float bregA[4][4], bregB[4][4];
    float bsq[4] = {0.f, 0.f, 0.f, 0.f};

#define LOAD_B(BREG, T) do {                                                   \
    _Pragma("unroll")                                                          \
    for (int i = 0; i < 4; ++i) {                                              \
        const float* p = W + b_go[i] + (T) * (BK * CC);                        \
        BREG[i][0] = p[0];      BREG[i][1] = p[CC];                            \
        BREG[i][2] = p[2 * CC]; BREG[i][3] = p[3 * CC];                        \
    } } while (0)

#define GLL_A(T) do {                                                          \
    unsigned char* A_nxt = bufA + ((T) & 1) * 32768;                           \
    const unsigned char* gsrc = imgA + (T) * 32768;                            \
    _Pragma("unroll")                                                          \
    for (int i = 0; i < 4; ++i)                                                \
        gll16(gsrc + i * 8192 + lds_u + lane * 16, A_nxt + i * 8192 + lds_u);  \
    } while (0)

#define WRITE_B(BREG, T) do {                                                  \
    unsigned char* dst = bufB + ((T) & 1) * 16384;                             \
    _Pragma("unroll")                                                          \
    for (int i = 0; i < 4; ++i) {                                              \
        bsq[i] += BREG[i][0] * BREG[i][0] + BREG[i][1] * BREG[i][1]            \
                + BREG[i][2] * BREG[i][2] + BREG[i][3] * BREG[i][3];           \
        unsigned w0, w1;                                                       \
        asm("v_cvt_pk_bf16_f32 %0, %1, %2" : "=v"(w0) : "v"(BREG[i][0]), "v"(BREG[i][1])); \
        asm("v_cvt_pk_bf16_f32 %0, %1, %2" : "=v"(w1) : "v"(BREG[i][2]), "v"(BREG[i][3])); \
        uint2 w; w.x = w0; w.y = w1;                                           \
        *(uint2*)(dst + b_ld[i]) = w;                                          \
    } } while (0)

#define COMPUTE(T) do {                                                        \
    const unsigned char* A_cur = bufA + ((T) & 1) * 32768;                     \
    const unsigned char* B_cur = bufB + ((T) & 1) * 16384;                     \
    _Pragma("unroll")                                                          \
    for (int ks = 0; ks < 2; ++ks) {                                           \
        bf16x8 af[4], bfr[4];                                                  \
        _Pragma("unroll")                                                      \
        for (int mf = 0; mf < 4; ++mf)                                         \
            af[mf] = *(const bf16x8*)(A_cur + swz(wm * 64 + mf * 16 + lr, ks * 64 + lg * 16)); \
        _Pragma("unroll")                                                      \
        for (int nf = 0; nf < 4; ++nf)                                         \
            bfr[nf] = *(const bf16x8*)(B_cur + swz(wn * 64 + nf * 16 + lr, ks * 64 + lg * 16)); \
        _Pragma("unroll")                                                      \
        for (int mf = 0; mf < 4; ++mf)                                         \
            _Pragma("unroll")                                                  \
            for (int nf = 0; nf < 4; ++nf)                                     \
                acc[mf][nf] = __builtin_amdgcn_mfma_f32_16x16x32_bf16(         \
                    bfr[nf], af[mf], acc[mf][nf], 0, 0, 0);                    \
    } } while (0)

// per-iter body; BC = regs holding B(T+1) (written now), BN_ = regs receiving B(T+2)
#define KBODY(T, BC, BN_) do {                                                 \
    if ((T) + 1 < KSTEPS) GLL_A((T) + 1);          /* glls BEFORE B loads! */  \
    if ((T) + 2 < KSTEPS) LOAD_B(BN_, (T) + 2);                                \
    __builtin_amdgcn_sched_barrier(0);                                         \
    COMPUTE(T);                                                                \
    if ((T) + 1 < KSTEPS) {                                                    \
        WRITE_B(BC, (T) + 1);                                                  \
        if ((T) + 2 < KSTEPS) { asm volatile("s_waitcnt vmcnt(16)" ::: "memory"); } \
        else                  { asm volatile("s_waitcnt vmcnt(0)"  ::: "memory"); } \
        __builtin_amdgcn_sched_barrier(0);                                     \
        asm volatile("s_waitcnt lgkmcnt(0)" ::: "memory");                     \
        __builtin_amdgcn_sched_barrier(0);                                     \
        __builtin_amdgcn_s_barrier();                                          \
        __builtin_amdgcn_sched_barrier(0);                                     \
    } } while (0)

    f32x4 acc[4][4];
    #pragma unroll
    for (int mf = 0; mf < 4; ++mf)
        #pragma unroll
        for (int nf = 0; nf < 4; ++nf)
            acc[mf][nf] = (f32x4)0.f;

    // ---- prologue: B(0)->bregA [ops 1-16], A(0) glls [17-20], B(1)->bregB [21-36]
    LOAD_B(bregA, 0);
    GLL_A(0);
    LOAD_B(bregB, 1);
    WRITE_B(bregA, 0);                         // compiler waits vmcnt(20) for bregA
    asm volatile("s_waitcnt vmcnt(16)" ::: "memory");   // drain A(0) glls, keep B(1)
    __builtin_amdgcn_sched_barrier(0);
    asm volatile("s_waitcnt lgkmcnt(0)" ::: "memory");
    __builtin_amdgcn_sched_barrier(0);
    __builtin_amdgcn_s_barrier();
    __builtin_amdgcn_sched_barrier(0);

    KBODY(0, bregB, bregA);
    KBODY(1, bregA, bregB);
    KBODY(2, bregB, bregA);
    KBODY(3, bregA, bregB);
    KBODY(4, bregB, bregA);
    KBODY(5, bregA, bregB);
    KBODY(6, bregB, bregA);
    KBODY(7, bregA, bregB);

    // ---- deterministic column-norm reduction (reuse bufB) ----
    __syncthreads();
    float* part = (float*)bufB;                // [16][128] floats = 8KB
    #pragma unroll
    for (int i = 0; i < 4; ++i)
        part[tid + i * 512] = bsq[i];          // slot = kq*128+n, unique owner
    __syncthreads();
    if (tid < BN) {
        float s = 0.f;
        #pragma unroll
        for (int k = 0; k < 16; ++k)
            s += part[k * BN + tid];           // fixed order -> deterministic
        rn[tid] = rsqrtf(fmaxf(s, 1e-12f));
    }
    __syncthreads();

    // ---- epilogue: LDS-staged -> 512B-aligned full-sector NON-TEMPORAL stores ----
    // (nt keeps the 200MB out-stream from evicting W out of the 256MB LLC)
    float* stag = (float*)bufA;                // 32 rows x 132 floats
    #pragma unroll
    for (int rd = 0; rd < 8; ++rd) {
        if (wm == (rd >> 1)) {
            #pragma unroll
            for (int f = 0; f < 2; ++f) {
                const int mf = (rd & 1) * 2 + f;
                const int ml = f * 16 + lr;
                #pragma unroll
                for (int nf = 0; nf < 4; ++nf) {
                    const int nl = wn * 64 + nf * 16 + lg * 4;
                    const f32x4 rn4 = *(const f32x4*)(rn + nl);
                    f32x4 o;
                    #pragma unroll
                    for (int r = 0; r < 4; ++r)
                        o[r] = acc[mf][nf][r] * rn4[r];
                    *(f32x4*)(stag + ml * 132 + nl) = o;
                }
            }
        }
        __syncthreads();
        #pragma unroll
        for (int j = tid; j < 1024; j += 512) {
            const int m = j >> 5;
            const int n = (j & 31) * 4;
            if (N0 + n + 4 <= CC) {
                f32x4 o = *(const f32x4*)(stag + m * 132 + n);
                __builtin_nontemporal_store(o,
                    (f32x4*)(out + (size_t)(M0 + rd * 32 + m) * CC + N0 + n));
            }
        }
        __syncthreads();
    }
}

// ---------------- K3: margin fixup at label positions ----------------
__global__ __launch_bounds__(512) void k_fix(const int* __restrict__ lab,
                                             float* __restrict__ out) {
    const int b = threadIdx.x;
    const int c = lab[b];
    const size_t idx = (size_t)b * CC + c;
    float t = out[idx];
    t = fminf(fmaxf(t, -1.f), 1.f);
    float th = acosf(t) + MARGIN2;
    th = fminf(th, PI_F);              // min(t, t + (pi - stopgrad(t))) value-wise
    out[idx] = cosf(th);               // M3 == 0: no additive term
}

extern "C" void kernel_launch(void* const* d_in, const int* in_sizes, int n_in,
                              void* d_out, int out_size, void* d_ws, size_t ws_size,
                              hipStream_t stream) {
    const float* x   = (const float*)d_in[0];
    const float* W   = (const float*)d_in[1];
    const int*   lab = (const int*)d_in[2];
    float* out = (float*)d_out;

    unsigned char* img = (unsigned char*)d_ws;   // 512KB pre-swizzled xn images

    k_norm_x<<<dim3(BB / 4), dim3(256), 0, stream>>>(x, img);
    k_gemm<<<dim3(GRID), dim3(512), 0, stream>>>(img, W, out);
    k_fix<<<dim3(1), dim3(512), 0, stream>>>(lab, out);
}